// Round 5
// baseline (1087.833 us; speedup 1.0000x reference)
//
#include <hip/hip_runtime.h>
#include <math.h>

#define T_TOTAL 1825
#define WARMUP_T 365
#define T_OUT (T_TOTAL - WARMUP_T)
#define NB 10000
#define HALF 5000

// Two basins per thread (b and b+5000): two fully independent dependence
// chains give the in-order wave issue stream enough ILP to fill the ~4-cyc
// dep-latency bubbles that limited the 1-basin/thread version (R4: 685
// cyc/step at only ~50% SIMD issue density).

struct Prm {
    float kc, pctim, adimp, uztwm, uzfwm, lztwm, lzfsm, lzfpm, pfree, riva,
          zperc, rexp, uzk, lzsk, lzpk, ci, cgs, cgp;
    float inv_uztwm, inv_lztwm, inv_uzfwm, inv_uzlz, uz_sum, lzall, inv_lzall,
          lzfsfp, ratio_fp, inv_lzfpm, inv_lzfsm, pbase, parea,
          omci, omcgs, omcgp, c1, c2, c3;
};

struct St {
    float auztw, alztw, uztw, uzfw, lztw, lzfs, lzfp, qs, qi, qgs, qgp, o_prev;
};

__device__ __forceinline__ void load_prm(const float* __restrict__ pr, Prm& P)
{
    // keep (hi-lo) as fp32 expressions so constant folding matches numpy fp32
    P.kc    = 0.1f   + pr[0]  * (1.2f - 0.1f);
    P.pctim = 0.0f   + pr[1]  * (0.1f - 0.0f);
    P.adimp = 0.0f   + pr[2]  * (0.3f - 0.0f);
    P.uztwm = 10.0f  + pr[3]  * (100.0f - 10.0f);
    P.uzfwm = 10.0f  + pr[4]  * (100.0f - 10.0f);
    P.lztwm = 50.0f  + pr[5]  * (400.0f - 50.0f);
    P.lzfsm = 10.0f  + pr[6]  * (100.0f - 10.0f);
    P.lzfpm = 50.0f  + pr[7]  * (1000.0f - 50.0f);
    P.pfree = 0.0f   + pr[9]  * (0.5f - 0.0f);
    P.riva  = 0.0f   + pr[10] * (0.1f - 0.0f);
    P.zperc = 5.0f   + pr[11] * (350.0f - 5.0f);
    P.rexp  = 1.0f   + pr[12] * (4.0f - 1.0f);
    P.uzk   = 0.1f   + pr[13] * (0.5f - 0.1f);
    P.lzsk  = 0.01f  + pr[14] * (0.35f - 0.01f);
    P.lzpk  = 0.001f + pr[15] * (0.05f - 0.001f);
    P.ci    = 0.5f   + pr[16] * (0.9f - 0.5f);
    P.cgs   = 0.95f  + pr[17] * (0.998f - 0.95f);
    P.cgp   = 0.98f  + pr[18] * (0.998f - 0.98f);
    const float ke = 0.0f + pr[19] * (1.0f - 0.0f);
    const float xe = 0.0f + pr[20] * (0.5f - 0.0f);

    P.inv_uztwm = 1.0f / P.uztwm;
    P.inv_lztwm = 1.0f / P.lztwm;
    P.inv_uzfwm = 1.0f / P.uzfwm;
    P.inv_uzlz  = 1.0f / (P.uztwm + P.lztwm);
    P.uz_sum    = P.uztwm + P.uzfwm;
    P.lzall     = P.lzfsm + P.lzfpm + P.lztwm;
    P.inv_lzall = 1.0f / P.lzall;
    P.lzfsfp    = P.lzfsm + P.lzfpm;
    P.ratio_fp  = P.lzfpm / P.lzfsfp;
    P.inv_lzfpm = 1.0f / P.lzfpm;
    P.inv_lzfsm = 1.0f / P.lzfsm;
    P.pbase     = P.lzfsm * P.lzsk + P.lzfpm * P.lzpk;
    P.parea     = 1.0f - P.pctim - P.adimp;
    P.omci      = 1.0f - P.ci;
    P.omcgs     = 1.0f - P.cgs;
    P.omcgp     = 1.0f - P.cgp;
    const float dt    = 0.5f;
    const float denom = ke * (1.0f - xe) + dt;
    P.c1 = (ke * xe + dt) / denom;
    P.c2 = (dt - ke * xe) / denom;
    P.c3 = (ke * (1.0f - xe) - dt) / denom;
}

template<bool STORE>
__device__ __forceinline__ void sac_step(const Prm& P, St& S, const float2 pe,
                                         float* __restrict__ qp,
                                         float* __restrict__ eo)
{
    const float p = fmaxf(pe.x, 0.0f);
    // inputs uniform[0,20]/[0,6]: nan_to_num+max(.,0) == max(.,0)
    const float e = fmaxf(pe.y, 0.0f);
    const float ep = P.kc * e;

    // --- ADIMP water balance ---
    const float ae1  = fminf(S.auztw, ep * (S.auztw * P.inv_uztwm));
    const float ae3  = fmaxf((ep - ae1) * (S.alztw * P.inv_uzlz), 0.0f);
    const float tp   = (S.auztw - ae1) + p;                 // shared subexpr
    const float pav  = fmaxf(tp - P.uztwm, 0.0f);
    const float alz3 = S.alztw - ae3;
    const float adsur = fmaxf(pav * (alz3 * P.inv_lztwm), 0.0f);
    const float v_   = (pav - adsur) + alz3;                // shared subexpr
    const float ars  = fmaxf(v_ - P.lztwm, 0.0f);
    const float auztw_n = fmaxf(fminf(P.uztwm, tp), 0.0f);
    const float alztw_n = fmaxf(fminf(P.lztwm, v_), 0.0f);

    // --- coef (independent: only lzfs/lzfp carries) ---
    const float gp_ = 1.0f - S.lzfp * P.inv_lzfpm;
    const float gs_ = 1.0f - S.lzfs * P.inv_lzfsm;
    float coef = P.ratio_fp * (2.0f * gp_) * __builtin_amdgcn_rcpf(gp_ + gs_);
    coef = fminf(coef, 1.0f);

    // --- pervious-area ET ---
    const float e1  = fminf(S.uztw, ep * (S.uztw * P.inv_uztwm));
    const float e2  = fmaxf(fminf(S.uzfw, ep - e1), 0.0f);
    const float e3  = fmaxf((ep - e1 - e2) * (S.lztw * P.inv_uzlz), 0.0f);
    const float lt1 = fmaxf(S.lztw - e3, 0.0f);

    // --- upper zone ---
    const float u_ = (S.uztw - e1) + p;                     // shared subexpr
    const float uz_avail = u_ + (S.uzfw - e2);
    const float rs = fmaxf(uz_avail - P.uz_sum, 0.0f) * P.parea;
    const float ut = fmaxf(fminf(P.uztwm, u_), 0.0f);
    float uf = fmaxf(fminf(P.uzfwm, uz_avail - ut), 0.0f);
    const float ri = uf * P.uzk;
    uf = uf - ri;                       // ri = uf*uzk <= uf: max(.,0) redundant

    // --- percolation ---
    const float lzsum = S.lzfs + S.lzfp + lt1;
    const float defr  = fmaxf(1.0f - lzsum * P.inv_lzall, 0.0f);
    // defr^rexp = exp2(rexp*log2(defr)); log2(0)=-inf -> exp2=0: correct.
    const float dpow  = __builtin_amdgcn_exp2f(P.rexp * __builtin_amdgcn_logf(defr));
    const float perc  = P.pbase * (1.0f + P.zperc * dpow) * uf * P.inv_uzfwm;
    const float rate  = fmaxf(fminf(perc, P.lzall - lzsum), 0.0f);
    uf = fmaxf(uf - rate, 0.0f);

    const float fx = fmaxf(fminf(P.lzfsfp - (S.lzfs + S.lzfp),
                                 fmaxf(rate - (P.lztwm - lt1), rate * P.pfree)),
                           0.0f);
    const float perct = rate - fx;
    const float percp = fmaxf(fminf(P.lzfpm - S.lzfp,
                                    fmaxf(fx - (P.lzfsm - S.lzfs), coef * fx)),
                              0.0f);
    const float percs = fmaxf(fx - percp, 0.0f);

    // --- lower zone + baseflow ---
    const float lt = fminf(lt1 + perct, P.lztwm);
    float ls = S.lzfs + percs;
    float lp = S.lzfp + percp;
    const float rgs = ls * P.lzsk;
    ls = ls - rgs;                      // rgs = ls*lzsk <= ls: max redundant
    const float rgp = lp * P.lzpk;
    lp = lp - rgp;

    // --- routing ---
    const float i1 = (S.qs + S.qi) + (S.qgs + S.qgp);
    S.qs  = (P.pctim * p + adsur * P.adimp) + (ars * P.adimp + rs);
    S.qi  = P.ci  * S.qi  + P.omci  * (ri  * P.parea);
    S.qgs = P.cgs * S.qgs + P.omcgs * (rgs * P.parea);
    S.qgp = P.cgp * S.qgp + P.omcgp * (rgp * P.parea);
    const float i2 = (S.qs + S.qi) + (S.qgs + S.qgp);
    const float o2 = P.c1 * i1 + P.c2 * i2 + P.c3 * S.o_prev;
    S.o_prev = o2;

    if (STORE) {
        const float et = (P.pctim * ep + ae1) + (ae3 + e1) + (e2 + e3)
                       + P.riva * ep;
        *qp = o2;
        *eo = et;
    }

    // --- commit carry ---
    S.auztw = auztw_n; S.alztw = alztw_n;
    S.uztw = ut; S.uzfw = uf; S.lztw = lt; S.lzfs = ls; S.lzfp = lp;
}

__device__ __forceinline__ void init_state(St& S)
{
    S.auztw = S.alztw = S.uztw = S.uzfw = S.lztw = 0.01f;
    S.lzfs = S.lzfp = S.qs = S.qi = S.qgs = S.qgp = S.o_prev = 0.01f;
}

__global__ __launch_bounds__(64, 1)
void sac_kernel(const float* __restrict__ p_and_e,
                const float* __restrict__ params,
                float* __restrict__ out)
{
    const int b = blockIdx.x * blockDim.x + threadIdx.x;
    if (b >= HALF) return;

    Prm PA, PB;
    load_prm(params + (size_t)b * 21, PA);
    load_prm(params + (size_t)(b + HALF) * 21, PB);

    St A, B;
    init_state(A);
    init_state(B);

    const float2* __restrict__ pe2 = (const float2*)p_and_e;
    float* __restrict__ q_out = out;
    float* __restrict__ e_out = out + (size_t)T_OUT * NB;

    unsigned lidx = (unsigned)b;   // float2-element index, row t, column b
    unsigned sidx = (unsigned)b;   // float-element index into output rows

    // prime pipeline: t = 0..3 for both basins
    float2 a0 = pe2[lidx];            float2 b0 = pe2[lidx + HALF];
    float2 a1 = pe2[lidx + 1u*NB];    float2 b1 = pe2[lidx + 1u*NB + HALF];
    float2 a2 = pe2[lidx + 2u*NB];    float2 b2 = pe2[lidx + 2u*NB + HALF];
    float2 a3 = pe2[lidx + 3u*NB];    float2 b3 = pe2[lidx + 3u*NB + HALF];
    lidx += 4u * NB;

    // ---- warmup: 91 groups of 4 -> t = 0..363 (no stores) ----
    for (int g = 0; g < 91; ++g) {
        const float2 na0 = pe2[lidx];           const float2 nb0 = pe2[lidx + HALF];
        const float2 na1 = pe2[lidx + 1u*NB];   const float2 nb1 = pe2[lidx + 1u*NB + HALF];
        const float2 na2 = pe2[lidx + 2u*NB];   const float2 nb2 = pe2[lidx + 2u*NB + HALF];
        const float2 na3 = pe2[lidx + 3u*NB];   const float2 nb3 = pe2[lidx + 3u*NB + HALF];
        lidx += 4u * NB;
        sac_step<false>(PA, A, a0, nullptr, nullptr);
        sac_step<false>(PB, B, b0, nullptr, nullptr);
        sac_step<false>(PA, A, a1, nullptr, nullptr);
        sac_step<false>(PB, B, b1, nullptr, nullptr);
        sac_step<false>(PA, A, a2, nullptr, nullptr);
        sac_step<false>(PB, B, b2, nullptr, nullptr);
        sac_step<false>(PA, A, a3, nullptr, nullptr);
        sac_step<false>(PB, B, b3, nullptr, nullptr);
        a0 = na0; a1 = na1; a2 = na2; a3 = na3;
        b0 = nb0; b1 = nb1; b2 = nb2; b3 = nb3;
    }
    // t = 364 (last warmup step): consume a0/b0, refill with t = 368
    {
        const float2 na = pe2[lidx];
        const float2 nb = pe2[lidx + HALF];
        lidx += NB;
        sac_step<false>(PA, A, a0, nullptr, nullptr);
        sac_step<false>(PB, B, b0, nullptr, nullptr);
        a0 = a1; a1 = a2; a2 = a3; a3 = na;
        b0 = b1; b1 = b2; b2 = b3; b3 = nb;
    }

    // ---- main: 364 groups of 4 -> t = 365..1820 (stores) ----
    // last group (g=363) prefetches t=1821..1824 — exactly in range.
    for (int g = 0; g < 364; ++g) {
        const float2 na0 = pe2[lidx];           const float2 nb0 = pe2[lidx + HALF];
        const float2 na1 = pe2[lidx + 1u*NB];   const float2 nb1 = pe2[lidx + 1u*NB + HALF];
        const float2 na2 = pe2[lidx + 2u*NB];   const float2 nb2 = pe2[lidx + 2u*NB + HALF];
        const float2 na3 = pe2[lidx + 3u*NB];   const float2 nb3 = pe2[lidx + 3u*NB + HALF];
        lidx += 4u * NB;
        sac_step<true>(PA, A, a0, q_out + sidx,        e_out + sidx);
        sac_step<true>(PB, B, b0, q_out + sidx + HALF, e_out + sidx + HALF);
        sidx += NB;
        sac_step<true>(PA, A, a1, q_out + sidx,        e_out + sidx);
        sac_step<true>(PB, B, b1, q_out + sidx + HALF, e_out + sidx + HALF);
        sidx += NB;
        sac_step<true>(PA, A, a2, q_out + sidx,        e_out + sidx);
        sac_step<true>(PB, B, b2, q_out + sidx + HALF, e_out + sidx + HALF);
        sidx += NB;
        sac_step<true>(PA, A, a3, q_out + sidx,        e_out + sidx);
        sac_step<true>(PB, B, b3, q_out + sidx + HALF, e_out + sidx + HALF);
        sidx += NB;
        a0 = na0; a1 = na1; a2 = na2; a3 = na3;
        b0 = nb0; b1 = nb1; b2 = nb2; b3 = nb3;
    }
    // tail: t = 1821..1824
    sac_step<true>(PA, A, a0, q_out + sidx,        e_out + sidx);
    sac_step<true>(PB, B, b0, q_out + sidx + HALF, e_out + sidx + HALF);
    sidx += NB;
    sac_step<true>(PA, A, a1, q_out + sidx,        e_out + sidx);
    sac_step<true>(PB, B, b1, q_out + sidx + HALF, e_out + sidx + HALF);
    sidx += NB;
    sac_step<true>(PA, A, a2, q_out + sidx,        e_out + sidx);
    sac_step<true>(PB, B, b2, q_out + sidx + HALF, e_out + sidx + HALF);
    sidx += NB;
    sac_step<true>(PA, A, a3, q_out + sidx,        e_out + sidx);
    sac_step<true>(PB, B, b3, q_out + sidx + HALF, e_out + sidx + HALF);
}

extern "C" void kernel_launch(void* const* d_in, const int* in_sizes, int n_in,
                              void* d_out, int out_size, void* d_ws, size_t ws_size,
                              hipStream_t stream) {
    const float* p_and_e = (const float*)d_in[0];   // (1825, 10000, 2) f32
    const float* params  = (const float*)d_in[1];   // (10000, 21) f32
    float* out = (float*)d_out;                     // (2, 1460, 10000) f32

    const int block = 64;
    const int grid = (HALF + block - 1) / block;    // 79 blocks, 2 basins/thread
    sac_kernel<<<grid, block, 0, stream>>>(p_and_e, params, out);
}